// Round 2
// baseline (402.465 us; speedup 1.0000x reference)
//
#include <hip/hip_runtime.h>
#include <stdint.h>

// Problem constants (fixed by the reference)
#define CC   21        // n_classes
#define HWp  262144    // H*W = 512*512 (2^18)
#define NPIX 2097152   // B*H*W
#define CMS  24        // padded cmT row stride (16B-aligned rows for b128 broadcast reads)
#define PAD  258       // stage row stride; even (float2-aligned), 258 % 32 == 2
#define PXB  512       // pixels per block (256 threads x 2 px)
#define NT   256

// post_i = p_i * (CM . c)_i / sum_i p_i * (CM . c)_i
// (row-normalizations of p and c cancel in the final normalization)
//
// Round-2 focus: memory-level parallelism. Round-1 had ideal traffic
// (WRITE exactly 176MB) but VGPR=36 -> ~1 load in flight per wave ->
// 2.6 TB/s (41% of achievable). Here: float2 loads (512B/wave-instr)
// + explicit 7-deep double-buffered load batches + VGPR headroom.

template<int J0>
__device__ __forceinline__ void load7(const float* __restrict__ src, int base, float2* buf) {
#pragma unroll
    for (int u = 0; u < 7; u++)
        buf[u] = *(const float2*)(src + base + (J0 + u) * HWp);
}

template<int J0>
__device__ __forceinline__ void fma7(const float* cmT, const float2* buf, float2* q) {
#pragma unroll
    for (int u = 0; u < 7; u++) {
        const float* wrow = &cmT[(J0 + u) * CMS];   // LDS broadcast, b128-friendly
        const float cx = buf[u].x, cy = buf[u].y;
#pragma unroll
        for (int i = 0; i < CC; i++) {
            q[i].x = fmaf(wrow[i], cx, q[i].x);
            q[i].y = fmaf(wrow[i], cy, q[i].y);
        }
    }
}

template<int I0>
__device__ __forceinline__ void mul7(const float2* buf, float2* q, float& sx, float& sy) {
#pragma unroll
    for (int u = 0; u < 7; u++) {
        q[I0 + u].x *= buf[u].x; sx += q[I0 + u].x;
        q[I0 + u].y *= buf[u].y; sy += q[I0 + u].y;
    }
}

__global__ __launch_bounds__(256, 5)
void ep_kernel(const float* __restrict__ prior,
               const float* __restrict__ current,
               const float* __restrict__ cm,
               float* __restrict__ out)
{
    // cmT[j*CMS + i] = CM[i][j], rows padded to 24 floats (96B) for aligned b128 reads
    __shared__ __align__(16) float cmT[CC * CMS];
    // stage[i*PAD + px]: normalized output for (channel i, block-phase-local pixel px)
    __shared__ __align__(16) float stage[CC * PAD];

    const int tid = threadIdx.x;
    for (int k = tid; k < CC * CMS; k += NT) {
        int j = k / CMS, i = k - j * CMS;
        cmT[k] = (i < CC) ? cm[i * CC + j] : 0.f;
    }
    __syncthreads();

    const int n0   = blockIdx.x * PXB + tid * 2;  // 2 consecutive pixels per thread
    const int b    = n0 >> 18;                    // n0 / HWp
    const int hw   = n0 & (HWp - 1);
    const int base = b * (CC << 18) + hw;         // + c*HWp per channel; fits int

    float2 q[CC];
#pragma unroll
    for (int i = 0; i < CC; i++) { q[i].x = 0.f; q[i].y = 0.f; }

    // Software-pipelined: two 7-deep load buffers, prior loads issued
    // before the last current-FMA block so the memory pipe never drains.
    float2 A[7], Bb[7];
    load7<0>(current, base, A);
    load7<7>(current, base, Bb);
    fma7<0>(cmT, A, q);
    load7<14>(current, base, A);
    fma7<7>(cmT, Bb, q);
    load7<0>(prior, base, Bb);        // start prior stream early
    fma7<14>(cmT, A, q);

    float sx = 0.f, sy = 0.f;
    load7<7>(prior, base, A);
    mul7<0>(Bb, q, sx, sy);
    load7<14>(prior, base, Bb);
    mul7<7>(A, q, sx, sy);
    mul7<14>(Bb, q, sx, sy);

    const float rx = 1.f / sx, ry = 1.f / sy;

    // Two-phase transposed epilogue: phase h stages pixels [h*256, h*256+256)
    // of this block (owned by threads [h*128,(h+1)*128)), then all threads
    // copy 5376 contiguous output floats with lane-consecutive stores.
    const int bb = blockIdx.x * (PXB * CC);
#pragma unroll
    for (int h = 0; h < 2; h++) {
        if ((tid >> 7) == h) {
            const int px = (tid & 127) * 2;       // phase-local pixel column
            float2* srow;
#pragma unroll
            for (int i = 0; i < CC; i++) {
                srow = (float2*)&stage[i * PAD + px];   // 8B-aligned (PAD even)
                float2 v; v.x = q[i].x * rx; v.y = q[i].y * ry;
                *srow = v;
            }
        }
        __syncthreads();
#pragma unroll
        for (int it = 0; it < CC; it++) {
            int m = it * NT + tid;                // local output float index
            int t = m / CC;                       // magic-mul div by 21
            int i = m - t * CC;
            out[bb + h * (NT * CC) + m] = stage[i * PAD + t];
        }
        __syncthreads();
    }
}

extern "C" void kernel_launch(void* const* d_in, const int* in_sizes, int n_in,
                              void* d_out, int out_size, void* d_ws, size_t ws_size,
                              hipStream_t stream) {
    const float* prior   = (const float*)d_in[0];
    const float* current = (const float*)d_in[1];
    const float* cm      = (const float*)d_in[2];
    float* out           = (float*)d_out;

    dim3 grid(NPIX / PXB), block(NT);             // 4096 blocks, 2 px/thread
    ep_kernel<<<grid, block, 0, stream>>>(prior, current, cm, out);
}

// Round 3
// 401.412 us; speedup vs baseline: 1.0026x; 1.0026x over previous
//
#include <hip/hip_runtime.h>
#include <stdint.h>

// Problem constants (fixed by the reference)
#define CC    21        // n_classes
#define HWp   262144    // H*W = 512*512 (2^18)
#define NPIX  2097152   // B*H*W
#define CMS   24        // padded cmT row stride (16B-aligned rows -> b128 broadcast reads)
#define PAD   257       // stage row stride; 257 % 32 == 1 -> conflict-free write phase
#define NT    256

// post_i = p_i * (CM . c)_i / sum_i p_i * (CM . c)_i
// (row-normalizations of p and c cancel in the final normalization)
//
// Round-3 focus: compiler-proof memory-level parallelism.
// Rounds 1-2 proved traffic is ideal (WRITE exactly 176MB) but BW is stuck
// at ~2.5 TB/s because the compiler sinks register loads to their uses
// (~1 outstanding 256B load/wave). Fix: each wave burst-issues 42
// global_load_lds async ops (zero VGPR cost, cannot be compiler-sunk past
// the barrier) into per-wave-private LDS slots, then drains once.
// 10.5 KB in flight per wave; compute is then pure LDS->VALU.

__device__ __forceinline__ void async_copy4(float* lds_dst, const float* g_src) {
    // size=4: lane l writes its 4B to lds_dst + 4*l (wave-uniform base, linear)
    __builtin_amdgcn_global_load_lds(
        (__attribute__((address_space(1))) void*)(g_src),
        (__attribute__((address_space(3))) void*)(lds_dst),
        4, 0, 0);
}

__global__ __launch_bounds__(256, 3)
void ep_kernel(const float* __restrict__ prior,
               const float* __restrict__ current,
               const float* __restrict__ cm,
               float* __restrict__ out)
{
    // Input staging: ibuf[wave][slot][lane]; slots 0..20 = current, 21..41 = prior.
    // After pass 2 this region is dead and is reused as the transposed stage
    // buffer stage[21][PAD] (21588 B <= 43008 B), guarded by __syncthreads.
    __shared__ __align__(16) char smem[4 * 42 * 64 * sizeof(float)];   // 43008 B
    __shared__ __align__(16) float cmT[CC * CMS];                      // 2016 B

    float* const ib    = (float*)smem;
    float* const stage = (float*)smem;

    const int tid  = threadIdx.x;
    const int w    = tid >> 6;          // wave id (0..3)
    const int lane = tid & 63;

    const int n0   = blockIdx.x * NT + tid;   // pixel index, one per thread
    const int b    = n0 >> 18;                // n0 / HWp
    const int hw   = n0 & (HWp - 1);
    const int base = b * (CC << 18) + hw;     // + c*HWp per channel; fits int

    // ---- Burst-issue all 42 async loads (per-wave-private LDS slots) ----
    float* const wbuf = ib + (w * 42) * 64;   // this wave's region
    (void)lane;                               // HW supplies lane offset for LDS dest
#pragma unroll
    for (int j = 0; j < CC; j++)
        async_copy4(wbuf + j * 64, current + base + j * HWp);
#pragma unroll
    for (int i = 0; i < CC; i++)
        async_copy4(wbuf + (CC + i) * 64, prior + base + i * HWp);

    // ---- Cooperative CM transpose load (overlaps with async loads) ----
    for (int k = tid; k < CC * CMS; k += NT) {
        int j = k / CMS, i = k - j * CMS;
        cmT[k] = (i < CC) ? cm[i * CC + j] : 0.f;
    }
    __syncthreads();   // drains vmcnt: all 42 planes + cmT valid in LDS

    // ---- Pass 1: pred_i = sum_j CM[i][j] * c_j (all operands in LDS) ----
    float q[CC];
#pragma unroll
    for (int i = 0; i < CC; i++) q[i] = 0.f;

#pragma unroll
    for (int j = 0; j < CC; j++) {
        const float c = wbuf[j * 64 + lane];      // lane-consecutive: conflict-free
        const float* wrow = &cmT[j * CMS];        // uniform broadcast, b128-merged
#pragma unroll
        for (int i = 0; i < CC; i++) q[i] = fmaf(wrow[i], c, q[i]);
    }

    // ---- Pass 2: multiply prior, accumulate normalizer ----
    float s = 0.f;
#pragma unroll
    for (int i = 0; i < CC; i++) {
        const float p = wbuf[(CC + i) * 64 + lane];
        q[i] *= p;
        s += q[i];
    }
    const float r = 1.f / s;

    // ---- Transposed epilogue (round-1 proven): ibuf now dead, reuse as stage ----
    __syncthreads();   // all waves done reading ibuf before overwrite
#pragma unroll
    for (int i = 0; i < CC; i++) stage[i * PAD + tid] = q[i] * r;
    __syncthreads();

    // Coalesced copy-out: block owns 256*21 = 5376 contiguous output floats.
    const int bb = blockIdx.x * (NT * CC);
#pragma unroll
    for (int it = 0; it < CC; it++) {
        int m = it * NT + tid;                // local output float index
        int t = m / CC;                       // magic-mul div by 21
        int i = m - t * CC;
        out[bb + m] = stage[i * PAD + t];     // read bank = (i+t)%32: <=3-way, free-ish
    }
}

extern "C" void kernel_launch(void* const* d_in, const int* in_sizes, int n_in,
                              void* d_out, int out_size, void* d_ws, size_t ws_size,
                              hipStream_t stream) {
    const float* prior   = (const float*)d_in[0];
    const float* current = (const float*)d_in[1];
    const float* cm      = (const float*)d_in[2];
    float* out           = (float*)d_out;

    dim3 grid(NPIX / NT), block(NT);          // 8192 blocks, 1 px/thread
    ep_kernel<<<grid, block, 0, stream>>>(prior, current, cm, out);
}